// Round 1
// baseline (948.633 us; speedup 1.0000x reference)
//
#include <hip/hip_runtime.h>
#include <math.h>

#define B_ 64
#define L_ 512
#define E_ 256
#define O_ 256

// ---------------------------------------------------------------------------
// Kernel 1: fused QKV projection.
// grid (12, 512), block 256. Each block: 64 rows (one b, 64 l's) x 64 cols of
// one of {q,k,v}. Writes qT/kT as [b][o][l] (transposed) so the attention
// kernel can stage LDS tiles fully coalesced with no transpose; v as [b][l][o].
// ---------------------------------------------------------------------------
__global__ __launch_bounds__(256, 4)
void qkv_proj(const float* __restrict__ joint,
              const float* __restrict__ Wq,
              const float* __restrict__ Wk,
              const float* __restrict__ Wv,
              float* __restrict__ qT,
              float* __restrict__ kT,
              float* __restrict__ vv) {
  __shared__ float As[32][68];   // [k][row], pad 68 -> 16B-aligned b128 rows
  __shared__ float Bs[32][64];   // [k][col]

  const int t  = threadIdx.x;
  const int tx = t & 15, ty = t >> 4;
  const int nb = blockIdx.x;          // 0..11
  const int mb = blockIdx.y;          // 0..511
  const int which = nb >> 2;          // 0=q 1=k 2=v
  const int col0  = (nb & 3) * 64;
  const float* W = (which == 0) ? Wq : (which == 1) ? Wk : Wv;
  const int m0 = mb * 64;
  const int b  = m0 >> 9;             // 64 rows always within one batch
  const int l0 = m0 & 511;

  float acc[4][4] = {};

  for (int k0 = 0; k0 < E_; k0 += 32) {
    // stage A (joint) transposed into As[k][row]
#pragma unroll
    for (int r = 0; r < 2; ++r) {
      int idx = t + r * 256;          // over [64 rows][8 quads]
      int row = idx >> 3, quad = idx & 7;
      float4 f = *(const float4*)&joint[(size_t)(m0 + row) * E_ + k0 + quad * 4];
      As[quad * 4 + 0][row] = f.x;
      As[quad * 4 + 1][row] = f.y;
      As[quad * 4 + 2][row] = f.z;
      As[quad * 4 + 3][row] = f.w;
    }
    // stage B (weights), already [k][col]
#pragma unroll
    for (int r = 0; r < 2; ++r) {
      int idx = t + r * 256;          // over [32 k][16 quads]
      int kk = idx >> 4, quad = idx & 15;
      *(float4*)&Bs[kk][quad * 4] =
          *(const float4*)&W[(size_t)(k0 + kk) * O_ + col0 + quad * 4];
    }
    __syncthreads();
#pragma unroll 8
    for (int kk = 0; kk < 32; ++kk) {
      float4 a  = *(const float4*)&As[kk][ty * 4];
      float4 b4 = *(const float4*)&Bs[kk][tx * 4];
      const float* ap = (const float*)&a;
      const float* bp = (const float*)&b4;
#pragma unroll
      for (int i = 0; i < 4; ++i)
#pragma unroll
        for (int j = 0; j < 4; ++j)
          acc[i][j] = fmaf(ap[i], bp[j], acc[i][j]);
    }
    __syncthreads();
  }

  if (which < 2) {
    // q,k -> transposed [b][o][l]; float4 along l
    float* dst = (which == 0) ? qT : kT;
#pragma unroll
    for (int j = 0; j < 4; ++j) {
      int o = col0 + tx * 4 + j;
      float4 f = {acc[0][j], acc[1][j], acc[2][j], acc[3][j]};
      *(float4*)&dst[((size_t)b * O_ + o) * L_ + l0 + ty * 4] = f;
    }
  } else {
    // v -> [b][l][o]; float4 along o
#pragma unroll
    for (int i = 0; i < 4; ++i) {
      int l = l0 + ty * 4 + i;
      float4 f = {acc[i][0], acc[i][1], acc[i][2], acc[i][3]};
      *(float4*)&vv[((size_t)b * L_ + l) * O_ + col0 + tx * 4] = f;
    }
  }
}

// ---------------------------------------------------------------------------
// Kernel 2: flash-style attention with fused delta bias and post-softmax mask.
// grid (8, 64), block 256 (tx 0..15 = cols, ty 0..15 = row-quads).
// Per block: 64 q-rows of one batch; loop over 8 m-chunks of 64.
//   S = q.kT + sum(delta)  -> online softmax (denominator over ALL m)
//   P masked for m >= traj_len, rows l >= traj_len zeroed at epilogue.
// kv_s (64 KB) is time-shared: k-chunk [e][m] during S-GEMM, v-chunk [m][o]
// during PV. LDS total ~148 KB -> 1 block/CU.
// ---------------------------------------------------------------------------
__global__ __launch_bounds__(256, 1)
void attn_kernel(const float* __restrict__ qT,
                 const float* __restrict__ kT,
                 const float* __restrict__ vv,
                 const float* __restrict__ delta,
                 const int* __restrict__ traj_len,
                 float* __restrict__ out) {
  __shared__ float q_s[E_][64];        // 64 KB [e][l]
  __shared__ float kv_s[E_ * 64];      // 64 KB shared k/v staging
  __shared__ float p_s[64][68];        // 17 KB [m][l], pad for b128 reads

  const int t  = threadIdx.x;
  const int tx = t & 15, ty = t >> 4;
  const int lt = blockIdx.x;           // q-tile 0..7
  const int b  = blockIdx.y;           // 0..63
  const int l0 = lt * 64;
  const int T  = traj_len[b];

  // load q tile once: q_s[e][l]
#pragma unroll
  for (int r = 0; r < 16; ++r) {
    int idx = t + r * 256;             // [256 e][16 quads]
    int e = idx >> 4, quad = idx & 15;
    *(float4*)&q_s[e][quad * 4] =
        *(const float4*)&qT[((size_t)b * E_ + e) * L_ + l0 + quad * 4];
  }

  float4 acc[4][4] = {};               // [row i][o-block j4], o = j4*64+tx*4
  float run_max[4], run_sum[4];
#pragma unroll
  for (int i = 0; i < 4; ++i) { run_max[i] = -INFINITY; run_sum[i] = 0.f; }

  for (int mc = 0; mc < 8; ++mc) {
    const int m0 = mc * 64;
    __syncthreads();                   // prev PV done; kv_s free (also fences q_s load)

    // stage k chunk: kv_s[e][m]
#pragma unroll
    for (int r = 0; r < 16; ++r) {
      int idx = t + r * 256;
      int e = idx >> 4, quad = idx & 15;
      *(float4*)&kv_s[e * 64 + quad * 4] =
          *(const float4*)&kT[((size_t)b * E_ + e) * L_ + m0 + quad * 4];
    }
    __syncthreads();

    // prefetch delta (issued now, consumed after the GEMM -> latency hidden)
    float4 dl[4][4];
#pragma unroll
    for (int i = 0; i < 4; ++i)
#pragma unroll
      for (int j = 0; j < 4; ++j)
        dl[i][j] = *(const float4*)&delta[(((size_t)b * L_ + (l0 + ty * 4 + i)) * L_
                                           + (m0 + tx * 4 + j)) * 4];

    // S-GEMM: s[i][j] = sum_e q[l][e] * k[m][e]
    float s_[4][4] = {};
#pragma unroll 4
    for (int e = 0; e < E_; ++e) {
      float4 a  = *(const float4*)&q_s[e][ty * 4];
      float4 b4 = *(const float4*)&kv_s[e * 64 + tx * 4];
      const float* ap = (const float*)&a;
      const float* bp = (const float*)&b4;
#pragma unroll
      for (int i = 0; i < 4; ++i)
#pragma unroll
        for (int j = 0; j < 4; ++j)
          s_[i][j] = fmaf(ap[i], bp[j], s_[i][j]);
    }

    // add delta bias
#pragma unroll
    for (int i = 0; i < 4; ++i)
#pragma unroll
      for (int j = 0; j < 4; ++j)
        s_[i][j] += dl[i][j].x + dl[i][j].y + dl[i][j].z + dl[i][j].w;

    // online softmax update; P masked (m >= T -> 0) AFTER denominator accum
    float scale_[4];
#pragma unroll
    for (int i = 0; i < 4; ++i) {
      float m_ = fmaxf(fmaxf(s_[i][0], s_[i][1]), fmaxf(s_[i][2], s_[i][3]));
#pragma unroll
      for (int off = 8; off >= 1; off >>= 1)
        m_ = fmaxf(m_, __shfl_xor(m_, off));
      float nm = fmaxf(run_max[i], m_);
      scale_[i] = __expf(run_max[i] - nm);   // first iter: exp(-inf)=0
      run_max[i] = nm;
      float cs = 0.f;
#pragma unroll
      for (int j = 0; j < 4; ++j) {
        float p = __expf(s_[i][j] - nm);
        cs += p;                              // denominator: UNmasked
        bool mv = (m0 + tx * 4 + j) < T;
        p_s[tx * 4 + j][ty * 4 + i] = mv ? p : 0.f;
      }
#pragma unroll
      for (int off = 8; off >= 1; off >>= 1)
        cs += __shfl_xor(cs, off);
      run_sum[i] = run_sum[i] * scale_[i] + cs;
    }
    __syncthreads();                   // p_s written; kv_s reads done

    // stage v chunk: kv_s[m][o]
#pragma unroll
    for (int r = 0; r < 16; ++r) {
      int idx = t + r * 256;           // [64 m][64 quads]
      int m = idx >> 6, quad = idx & 63;
      *(float4*)&kv_s[m * 256 + quad * 4] =
          *(const float4*)&vv[((size_t)b * L_ + m0 + m) * O_ + quad * 4];
    }
    __syncthreads();

    // rescale accumulators, then PV accumulate
#pragma unroll
    for (int i = 0; i < 4; ++i) {
      float sc = scale_[i];
#pragma unroll
      for (int j4 = 0; j4 < 4; ++j4) {
        acc[i][j4].x *= sc; acc[i][j4].y *= sc;
        acc[i][j4].z *= sc; acc[i][j4].w *= sc;
      }
    }
#pragma unroll 2
    for (int m = 0; m < 64; ++m) {
      float4 a = *(const float4*)&p_s[m][ty * 4];
      const float* ap = (const float*)&a;
#pragma unroll
      for (int j4 = 0; j4 < 4; ++j4) {
        float4 v4 = *(const float4*)&kv_s[m * 256 + j4 * 64 + tx * 4];
#pragma unroll
        for (int i = 0; i < 4; ++i) {
          acc[i][j4].x = fmaf(ap[i], v4.x, acc[i][j4].x);
          acc[i][j4].y = fmaf(ap[i], v4.y, acc[i][j4].y);
          acc[i][j4].z = fmaf(ap[i], v4.z, acc[i][j4].z);
          acc[i][j4].w = fmaf(ap[i], v4.w, acc[i][j4].w);
        }
      }
    }
  }

  // epilogue: normalize by denominator, zero invalid rows
#pragma unroll
  for (int i = 0; i < 4; ++i) {
    int l = l0 + ty * 4 + i;
    float inv = (l < T) ? (1.0f / run_sum[i]) : 0.f;
#pragma unroll
    for (int j4 = 0; j4 < 4; ++j4) {
      float4 f = {acc[i][j4].x * inv, acc[i][j4].y * inv,
                  acc[i][j4].z * inv, acc[i][j4].w * inv};
      *(float4*)&out[((size_t)b * L_ + l) * O_ + j4 * 64 + tx * 4] = f;
    }
  }
}

extern "C" void kernel_launch(void* const* d_in, const int* in_sizes, int n_in,
                              void* d_out, int out_size, void* d_ws, size_t ws_size,
                              hipStream_t stream) {
  const float* joint    = (const float*)d_in[0];
  const float* delta    = (const float*)d_in[1];
  const int*   traj_len = (const int*)d_in[2];
  const float* Wq       = (const float*)d_in[3];
  const float* Wk       = (const float*)d_in[4];
  const float* Wv       = (const float*)d_in[5];
  float* out = (float*)d_out;

  float* qT = (float*)d_ws;                        // [B][O][L]
  float* kT = qT + (size_t)B_ * O_ * L_;           // [B][O][L]
  float* vw = kT + (size_t)B_ * O_ * L_;           // [B][L][O]

  qkv_proj<<<dim3(12, 512), 256, 0, stream>>>(joint, Wq, Wk, Wv, qT, kT, vw);
  attn_kernel<<<dim3(8, 64), 256, 0, stream>>>(qT, kT, vw, delta, traj_len, out);
}

// Round 4
// 482.422 us; speedup vs baseline: 1.9664x; 1.9664x over previous
//
#include <hip/hip_runtime.h>
#include <hip/hip_fp16.h>
#include <math.h>

#define B_ 64
#define L_ 512
#define E_ 256
#define O_ 256

typedef float  f4_t  __attribute__((ext_vector_type(4)));
typedef short  bf8_t __attribute__((ext_vector_type(8)));   // 8 bf16/fp16 (4 VGPR)
typedef unsigned int u32;
typedef unsigned int u32x4 __attribute__((ext_vector_type(4)));

__device__ __forceinline__ unsigned short f2bf(float x) {   // RNE f32->bf16
  u32 u = __float_as_uint(x);
  u32 r = u + 0x7fff + ((u >> 16) & 1);
  return (unsigned short)(r >> 16);
}
__device__ __forceinline__ float bf2f(unsigned short h) {
  return __uint_as_float(((u32)h) << 16);
}
__device__ __forceinline__ unsigned short f2h(float x) {    // RNE f32->fp16
  __half h = __float2half(x);
  return *reinterpret_cast<unsigned short*>(&h);
}
// XOR swizzle: spreads stride-power-of-2 LDS rows across banks (G4 / T2)
#define SWZ(byte, row) ((byte) ^ (((row) & 7) << 4))

// ---------------------------------------------------------------------------
// Kernel 0: build frag-packed, hi/lo-split, transposed W for the proj kernel.
// Layout per which: [(nt*8+kc)*2+hl][lane][8] bf16 so a proj B-frag load is
// one coalesced 1KB/wave global_load_dwordx4 (L2-resident, 768KB total).
// Element: o = nt*16 + (lane&15), e = kc*32 + (lane>>4)*8 + i.
// ---------------------------------------------------------------------------
__global__ void setup_w(const float* __restrict__ Wq, const float* __restrict__ Wk,
                        const float* __restrict__ Wv, unsigned short* __restrict__ WT) {
  __shared__ float w_s[64][65];
  const int t = threadIdx.x;
  const int which = blockIdx.x >> 4;
  const int tile  = blockIdx.x & 15;
  const int e0 = (tile >> 2) * 64, o0 = (tile & 3) * 64;
  const float* W = (which == 0) ? Wq : (which == 1) ? Wk : Wv;

  // [64 e-rows][16 f32x4] = 1024 items = 4 iters (64-col tile: 16 quads/row)
#pragma unroll
  for (int i = 0; i < 4; ++i) {
    int idx = t + i * 256;
    int row = idx >> 4, qd = idx & 15;
    f4_t f = *(const f4_t*)&W[(e0 + row) * O_ + o0 + qd * 4];
    w_s[row][qd * 4 + 0] = f.x; w_s[row][qd * 4 + 1] = f.y;
    w_s[row][qd * 4 + 2] = f.z; w_s[row][qd * 4 + 3] = f.w;
  }
  __syncthreads();

#pragma unroll
  for (int j = 0; j < 2; ++j) {
    int run = t + j * 256;             // [ntl 4][kcl 2][lane 64]
    int lane = run & 63, kcl = (run >> 6) & 1, ntl = (run >> 7) & 3;
    int o_l = ntl * 16 + (lane & 15);
    int e_l = kcl * 32 + ((lane >> 4) << 3);
    unsigned short h8[8], l8[8];
#pragma unroll
    for (int i = 0; i < 8; ++i) {
      float x = w_s[e_l + i][o_l];
      unsigned short h = f2bf(x);
      h8[i] = h; l8[i] = f2bf(x - bf2f(h));
    }
    int nt_g = (tile & 3) * 4 + ntl;
    int kc_g = (tile >> 2) * 2 + kcl;
    size_t base = (size_t)which * 131072 + ((nt_g * 8 + kc_g) * 2) * 512 + lane * 8;
#pragma unroll
    for (int i = 0; i < 8; ++i) { WT[base + i] = h8[i]; WT[base + 512 + i] = l8[i]; }
  }
}

// ---------------------------------------------------------------------------
// Kernel 1: QKV projection, split-bf16 3-pass MFMA (fp32-quality). grid 512
// (one per 64 rows), 256 thr, 4 waves x 64-col slabs. q,k stored as packed
// u32 (bf16 hi | lo<<16) [b][l][o]; v stored transposed fp16 [b][o][l].
// ---------------------------------------------------------------------------
__global__ __launch_bounds__(256, 2)
void qkv_proj(const float* __restrict__ joint, const unsigned short* __restrict__ WT,
              u32* __restrict__ qp, u32* __restrict__ kp, unsigned short* __restrict__ vT) {
  __shared__ unsigned short jh_s[64 * 256];   // 32KB, swizzled rows (512B)
  __shared__ unsigned short jl_s[64 * 256];   // 32KB
  __shared__ unsigned short vb_s[128 * 64];   // 16KB v-transpose bounce

  const int t = threadIdx.x;
  const int lane = t & 63, wid = t >> 6;
  const int m0 = blockIdx.x * 64;
  const int b = m0 >> 9, l0 = m0 & 511;

  // stage joint [64 rows][256 f32] -> hi/lo bf16 LDS (swizzled).
  // [64 rows][64 f32x4] = 4096 items = 16 iters of 256 thr.
  // (r2 bug: 16 iters with [64][16] decode -> row OOB; r3 bug: 4 iters left
  //  3/4 of LDS uninitialized -> NaN. Correct: 16 iters, row=idx>>6, qd=idx&63.)
#pragma unroll
  for (int i = 0; i < 16; ++i) {
    int idx = t + i * 256;
    int row = idx >> 6, qd = idx & 63;
    f4_t f = *(const f4_t*)&joint[(size_t)(m0 + row) * E_ + qd * 4];
    unsigned short h0 = f2bf(f.x), h1 = f2bf(f.y), h2 = f2bf(f.z), h3 = f2bf(f.w);
    uint2 hp = { (u32)h0 | ((u32)h1 << 16), (u32)h2 | ((u32)h3 << 16) };
    uint2 lp = { (u32)f2bf(f.x - bf2f(h0)) | ((u32)f2bf(f.y - bf2f(h1)) << 16),
                 (u32)f2bf(f.z - bf2f(h2)) | ((u32)f2bf(f.w - bf2f(h3)) << 16) };
    int byte = row * 512 + qd * 8;
    *(uint2*)((char*)jh_s + SWZ(byte, row)) = hp;
    *(uint2*)((char*)jl_s + SWZ(byte, row)) = lp;
  }
  __syncthreads();

  for (int which = 0; which < 3; ++which) {
    const unsigned short* WTw = WT + (size_t)which * 131072;
    f4_t acc[4][4];
#pragma unroll
    for (int i = 0; i < 4; ++i)
#pragma unroll
      for (int j = 0; j < 4; ++j) acc[i][j] = (f4_t)0.f;

#pragma unroll
    for (int kc = 0; kc < 8; ++kc) {
      bf8_t bh[4], bl[4], ah[4], al[4];
#pragma unroll
      for (int nt = 0; nt < 4; ++nt) {
        int ntg = wid * 4 + nt;
        size_t base = ((ntg * 8 + kc) * 2) * 512 + lane * 8;
        bh[nt] = *(const bf8_t*)(WTw + base);
        bl[nt] = *(const bf8_t*)(WTw + base + 512);
      }
#pragma unroll
      for (int mt = 0; mt < 4; ++mt) {
        int row = mt * 16 + (lane & 15);
        int byte = row * 512 + (kc * 32 + (lane >> 4) * 8) * 2;
        ah[mt] = *(const bf8_t*)((char*)jh_s + SWZ(byte, row));
        al[mt] = *(const bf8_t*)((char*)jl_s + SWZ(byte, row));
      }
#pragma unroll
      for (int mt = 0; mt < 4; ++mt)
#pragma unroll
        for (int nt = 0; nt < 4; ++nt) {
          acc[mt][nt] = __builtin_amdgcn_mfma_f32_16x16x32_bf16(ah[mt], bh[nt], acc[mt][nt], 0, 0, 0);
          acc[mt][nt] = __builtin_amdgcn_mfma_f32_16x16x32_bf16(al[mt], bh[nt], acc[mt][nt], 0, 0, 0);
          acc[mt][nt] = __builtin_amdgcn_mfma_f32_16x16x32_bf16(ah[mt], bl[nt], acc[mt][nt], 0, 0, 0);
        }
    }

    if (which < 2) {
      // q,k: packed u32 (hi | lo<<16), coalesced 64B per 16-lane group
      u32* dst = (which == 0) ? qp : kp;
#pragma unroll
      for (int mt = 0; mt < 4; ++mt)
#pragma unroll
        for (int nt = 0; nt < 4; ++nt) {
          int o = wid * 64 + nt * 16 + (lane & 15);
#pragma unroll
          for (int r = 0; r < 4; ++r) {
            int l = l0 + mt * 16 + (lane >> 4) * 4 + r;
            float v = acc[mt][nt][r];
            unsigned short h = f2bf(v);
            unsigned short lo = f2bf(v - bf2f(h));
            dst[((size_t)b * L_ + l) * O_ + o] = (u32)h | ((u32)lo << 16);
          }
        }
    } else {
      // v: bounce through LDS to store vT[b][o][l] fp16 coalesced, 2 rounds
#pragma unroll
      for (int half = 0; half < 2; ++half) {
        if ((wid >> 1) == half) {
#pragma unroll
          for (int mt = 0; mt < 4; ++mt)
#pragma unroll
            for (int nt = 0; nt < 4; ++nt) {
              int o_loc = (wid & 1) * 64 + nt * 16 + (lane & 15);
#pragma unroll
              for (int r = 0; r < 4; ++r) {
                int l_loc = mt * 16 + (lane >> 4) * 4 + r;
                int byte = o_loc * 128 + l_loc * 2;
                *(unsigned short*)((char*)vb_s + SWZ(byte, o_loc)) = f2h(acc[mt][nt][r]);
              }
            }
        }
        __syncthreads();
        {
          int o_loc = t >> 1, seg = t & 1;
          int o = half * 128 + o_loc;
#pragma unroll
          for (int j = 0; j < 4; ++j) {
            int byte = o_loc * 128 + seg * 64 + j * 16;
            bf8_t v8 = *(const bf8_t*)((char*)vb_s + SWZ(byte, o_loc));
            *(bf8_t*)&vT[((size_t)b * O_ + o) * L_ + l0 + seg * 32 + j * 8] = v8;
          }
        }
        __syncthreads();
      }
    }
  }
}

// ---------------------------------------------------------------------------
// Kernel 2: flash attention. grid 512, b = bid&63 (all 8 l-tiles of a batch
// land on one XCD -> k/v L2 reuse), 256 thr / 4 waves; wave owns 16 q-rows,
// q hi/lo frags in registers. m-chunks of 32: swizzled kh/kl/v LDS (52KB ->
// 2 blocks/CU), delta streamed nontemporal (issued post-barrier, consumed
// post-QK). 3-pass split-bf16 QK; fp16 PV. Softmax-then-mask semantics.
// ---------------------------------------------------------------------------
__global__ __launch_bounds__(256, 2)
void attn(const u32* __restrict__ qp, const u32* __restrict__ kp,
          const unsigned short* __restrict__ vT, const float* __restrict__ delta,
          const int* __restrict__ traj_len, float* __restrict__ out) {
  __shared__ unsigned short kh_s[32 * 256];   // 16KB [m][o], swizzled
  __shared__ unsigned short kl_s[32 * 256];   // 16KB
  __shared__ unsigned short v_s[256 * 32];    // 16KB [o][m] fp16, swizzled
  __shared__ unsigned short p_s[64 * 32];     // 4KB  [l][m] fp16, wave-private rows

  const int t = threadIdx.x;
  const int lane = t & 63, wid = t >> 6;
  const int b = blockIdx.x & 63;
  const int l0 = (blockIdx.x >> 6) * 64;
  const int wl0 = l0 + wid * 16;
  const int T = traj_len[b];
  const int g = lane >> 4, c = lane & 15;

  // q A-frags in registers: 8 kc x (hi,lo)
  bf8_t qh[8], ql[8];
#pragma unroll
  for (int kc = 0; kc < 8; ++kc) {
    size_t base = ((size_t)b * L_ + (wl0 + c)) * O_ + kc * 32 + g * 8;
    u32x4 w0 = *(const u32x4*)&qp[base];
    u32x4 w1 = *(const u32x4*)&qp[base + 4];
    bf8_t h, l;
#pragma unroll
    for (int i = 0; i < 4; ++i) {
      h[i] = (short)(w0[i] & 0xffff); l[i] = (short)(w0[i] >> 16);
      h[i + 4] = (short)(w1[i] & 0xffff); l[i + 4] = (short)(w1[i] >> 16);
    }
    qh[kc] = h; ql[kc] = l;
  }

  f4_t accO[16];
#pragma unroll
  for (int i = 0; i < 16; ++i) accO[i] = (f4_t)0.f;
  float run_max[4] = { -INFINITY, -INFINITY, -INFINITY, -INFINITY };
  float run_sum[4] = { 0.f, 0.f, 0.f, 0.f };

  for (int mc = 0; mc < 16; ++mc) {
    const int m0 = mc * 32;

    // stage k chunk (unpack hi/lo): [32 m][32 oc of 8] = 1024 items = 4 iters
#pragma unroll
    for (int i = 0; i < 4; ++i) {
      int idx = t + i * 256;
      int m = idx >> 5, oc = idx & 31;
      size_t gbase = ((size_t)b * L_ + m0 + m) * O_ + oc * 8;
      u32x4 w0 = *(const u32x4*)&kp[gbase];
      u32x4 w1 = *(const u32x4*)&kp[gbase + 4];
      bf8_t h, l;
#pragma unroll
      for (int j = 0; j < 4; ++j) {
        h[j] = (short)(w0[j] & 0xffff); l[j] = (short)(w0[j] >> 16);
        h[j + 4] = (short)(w1[j] & 0xffff); l[j + 4] = (short)(w1[j] >> 16);
      }
      int byte = m * 512 + oc * 16;
      *(bf8_t*)((char*)kh_s + SWZ(byte, m)) = h;
      *(bf8_t*)((char*)kl_s + SWZ(byte, m)) = l;
    }
    // stage v chunk — v_s[o][m] from vT[b][o][m0..m0+31]
    {
      const unsigned short* src = &vT[((size_t)b * O_ + t) * L_ + m0];
#pragma unroll
      for (int j = 0; j < 4; ++j) {
        bf8_t v8 = *(const bf8_t*)(src + j * 8);
        int byte = t * 64 + j * 16;
        *(bf8_t*)((char*)v_s + SWZ(byte, t)) = v8;
      }
    }
    __syncthreads();   // stages visible

    // issue delta loads (nontemporal) — consumed after QK, latency hidden
    f4_t dl[2][4];
#pragma unroll
    for (int mt = 0; mt < 2; ++mt)
#pragma unroll
      for (int r = 0; r < 4; ++r) {
        int l = wl0 + g * 4 + r;
        int m = m0 + mt * 16 + c;
        dl[mt][r] = __builtin_nontemporal_load(
            (const f4_t*)&delta[(((size_t)b * L_ + l) * L_ + m) * 4]);
      }

    // QK: 3-pass split bf16
    f4_t sacc[2] = { (f4_t)0.f, (f4_t)0.f };
#pragma unroll
    for (int kc = 0; kc < 8; ++kc) {
#pragma unroll
      for (int mt = 0; mt < 2; ++mt) {
        int m = mt * 16 + c;
        int byte = m * 512 + (kc * 32 + g * 8) * 2;
        bf8_t kh = *(const bf8_t*)((char*)kh_s + SWZ(byte, m));
        bf8_t kl = *(const bf8_t*)((char*)kl_s + SWZ(byte, m));
        sacc[mt] = __builtin_amdgcn_mfma_f32_16x16x32_bf16(qh[kc], kh, sacc[mt], 0, 0, 0);
        sacc[mt] = __builtin_amdgcn_mfma_f32_16x16x32_bf16(ql[kc], kh, sacc[mt], 0, 0, 0);
        sacc[mt] = __builtin_amdgcn_mfma_f32_16x16x32_bf16(qh[kc], kl, sacc[mt], 0, 0, 0);
      }
    }

    // add delta bias
    float s[2][4];
#pragma unroll
    for (int mt = 0; mt < 2; ++mt)
#pragma unroll
      for (int r = 0; r < 4; ++r)
        s[mt][r] = sacc[mt][r] + (dl[mt][r].x + dl[mt][r].y + dl[mt][r].z + dl[mt][r].w);

    // online softmax (rows = g*4+r, reduce across the 16 lanes of group g)
    float scale_r[4];
#pragma unroll
    for (int r = 0; r < 4; ++r) {
      float mx = fmaxf(s[0][r], s[1][r]);
#pragma unroll
      for (int off = 8; off >= 1; off >>= 1) mx = fmaxf(mx, __shfl_xor(mx, off));
      float nm = fmaxf(run_max[r], mx);
      float sc = __expf(run_max[r] - nm);
      run_max[r] = nm; scale_r[r] = sc;
      float p0 = __expf(s[0][r] - nm);
      float p1 = __expf(s[1][r] - nm);
      float cs = p0 + p1;                      // denominator: UNmasked
#pragma unroll
      for (int off = 8; off >= 1; off >>= 1) cs += __shfl_xor(cs, off);
      run_sum[r] = run_sum[r] * sc + cs;
      // write P (masked AFTER denom) — rows are wave-private
      int l_loc = wid * 16 + g * 4 + r;
      float pv[2] = { p0, p1 };
#pragma unroll
      for (int mt = 0; mt < 2; ++mt) {
        int m_loc = mt * 16 + c;
        float pw = (m0 + m_loc < T) ? pv[mt] : 0.f;
        int byte = l_loc * 64 + m_loc * 2;
        *(unsigned short*)((char*)p_s + SWZ(byte, l_loc)) = f2h(pw);
      }
    }

    // rescale O accumulator
#pragma unroll
    for (int nt = 0; nt < 16; ++nt)
#pragma unroll
      for (int r = 0; r < 4; ++r) accO[nt][r] *= scale_r[r];

    // PV in fp16 (p_s rows are wave-private; v_s covered by stage barrier)
    {
      int l_loc = wid * 16 + c;
      int abyte = l_loc * 64 + g * 16;
      bf8_t pa = *(const bf8_t*)((char*)p_s + SWZ(abyte, l_loc));
#pragma unroll
      for (int nt = 0; nt < 16; ++nt) {
        int o_loc = nt * 16 + c;
        int bbyte = o_loc * 64 + g * 16;
        bf8_t vb = *(const bf8_t*)((char*)v_s + SWZ(bbyte, o_loc));
        accO[nt] = __builtin_amdgcn_mfma_f32_16x16x32_f16(pa, vb, accO[nt], 0, 0, 0);
      }
    }
    __syncthreads();   // k_s/v_s reads done before next stage
  }

  // epilogue: normalize, zero invalid rows
#pragma unroll
  for (int r = 0; r < 4; ++r) {
    int lg = wl0 + g * 4 + r;
    float inv = (lg < T) ? (1.0f / run_sum[r]) : 0.f;
#pragma unroll
    for (int nt = 0; nt < 16; ++nt) {
      int o = nt * 16 + c;
      out[((size_t)b * L_ + lg) * O_ + o] = accO[nt][r] * inv;
    }
  }
}

extern "C" void kernel_launch(void* const* d_in, const int* in_sizes, int n_in,
                              void* d_out, int out_size, void* d_ws, size_t ws_size,
                              hipStream_t stream) {
  const float* joint    = (const float*)d_in[0];
  const float* delta    = (const float*)d_in[1];
  const int*   traj_len = (const int*)d_in[2];
  const float* Wq       = (const float*)d_in[3];
  const float* Wk       = (const float*)d_in[4];
  const float* Wv       = (const float*)d_in[5];
  float* outp = (float*)d_out;

  u32* qp = (u32*)d_ws;                                    // [B][L][O] packed hi/lo bf16
  u32* kp = qp + (size_t)B_ * L_ * O_;                     // [B][L][O] packed hi/lo bf16
  unsigned short* vT = (unsigned short*)(kp + (size_t)B_ * L_ * O_);  // [B][O][L] fp16
  unsigned short* WT = vT + (size_t)B_ * O_ * L_;          // [3][16*8*2*64*8] bf16

  setup_w<<<48, 256, 0, stream>>>(Wq, Wk, Wv, WT);
  qkv_proj<<<512, 256, 0, stream>>>(joint, WT, qp, kp, vT);
  attn<<<512, 256, 0, stream>>>(qp, kp, vT, delta, traj_len, outp);
}